// Round 2
// baseline (15477.698 us; speedup 1.0000x reference)
//
#include <hip/hip_runtime.h>

// B=131072 independent LSTMs, T=40, H=40, in-dim 1, FC to C=4 + argmax.
// R2: R1 spilled all state to scratch (VGPR=36, WRITE_SIZE=1.66GB). Fix:
// h/c/nh as NAMED scalar variables via macro repetition -> guaranteed VGPRs.
// Weights at wave-uniform compile-time offsets -> s_load, FMA reads SGPR.

#define B_ 131072
#define T_ 40
#define H_ 40
#define C_ 4

__device__ __forceinline__ float fexp2f(float v) { return __builtin_amdgcn_exp2f(v); }
__device__ __forceinline__ float frcpf(float v)  { return __builtin_amdgcn_rcpf(v); }

// sigmoid(x) = 1/(1+2^(-x*log2 e)); exact tails 0/1
__device__ __forceinline__ float sigmf(float v) {
    return frcpf(1.0f + fexp2f(-1.44269504088896340736f * v));
}
// tanh(x) = 1 - 2/(1+2^(2x*log2 e)); exact tails +/-1
__device__ __forceinline__ float tanhf_(float v) {
    return 1.0f - 2.0f * frcpf(1.0f + fexp2f(2.88539008177792681472f * v));
}

#define RPTA(M) M(0) M(1) M(2) M(3) M(4) M(5) M(6) M(7) M(8) M(9) \
                M(10) M(11) M(12) M(13) M(14) M(15) M(16) M(17) M(18) M(19) \
                M(20) M(21) M(22) M(23) M(24) M(25) M(26) M(27) M(28) M(29) \
                M(30) M(31) M(32) M(33) M(34) M(35) M(36) M(37) M(38) M(39)
#define RPTB(M) M(0) M(1) M(2) M(3) M(4) M(5) M(6) M(7) M(8) M(9) \
                M(10) M(11) M(12) M(13) M(14) M(15) M(16) M(17) M(18) M(19) \
                M(20) M(21) M(22) M(23) M(24) M(25) M(26) M(27) M(28) M(29) \
                M(30) M(31) M(32) M(33) M(34) M(35) M(36) M(37) M(38) M(39)

__global__ __launch_bounds__(256, 2)
void lstm_fused_kernel(const float* __restrict__ x,
                       const float* __restrict__ W_ih,   // (160,1)
                       const float* __restrict__ W_hh,   // (160,40) row-major
                       const float* __restrict__ b_ih,   // (160,)
                       const float* __restrict__ b_hh,   // (160,)
                       const float* __restrict__ W_fc,   // (4,40) row-major
                       const float* __restrict__ b_fc,   // (4,)
                       float* __restrict__ out)          // [B*4 logits][B argmax-as-float]
{
    const int b = blockIdx.x * blockDim.x + threadIdx.x;
    const float* xr = x + (long)b * T_;

    // named-register LSTM state
#define DECLHC(i) float h##i = 0.0f; float c##i = 0.0f;
    RPTA(DECLHC)
#undef DECLHC

    float xt = xr[0];

#pragma unroll 1
    for (int t = 0; t < T_; ++t) {
        const int tn = (t + 1 < T_) ? (t + 1) : (T_ - 1);
        const float xnext = xr[tn];   // prefetch next scalar input

#define DECLNH(i) float nh##i;
        RPTA(DECLNH)
#undef DECLNH

        // 4-FMA MAC step at column k; W0..W3 are the four gate rows of unit j
#define MACK(k) \
        a0 = fmaf(h##k, W0[k], a0); \
        a1 = fmaf(h##k, W1[k], a1); \
        a2 = fmaf(h##k, W2[k], a2); \
        a3 = fmaf(h##k, W3[k], a3);

#define UNIT(j) { \
        const float* W0 = W_hh + (j) * H_; \
        const float* W1 = W_hh + (40 + (j)) * H_; \
        const float* W2 = W_hh + (80 + (j)) * H_; \
        const float* W3 = W_hh + (120 + (j)) * H_; \
        float a0 = fmaf(xt, W_ih[(j)],       b_ih[(j)]       + b_hh[(j)]); \
        float a1 = fmaf(xt, W_ih[40 + (j)],  b_ih[40 + (j)]  + b_hh[40 + (j)]); \
        float a2 = fmaf(xt, W_ih[80 + (j)],  b_ih[80 + (j)]  + b_hh[80 + (j)]); \
        float a3 = fmaf(xt, W_ih[120 + (j)], b_ih[120 + (j)] + b_hh[120 + (j)]); \
        RPTB(MACK) \
        const float ig = sigmf(a0); \
        const float fg = sigmf(a1); \
        const float gv = tanhf_(a2); \
        const float og = sigmf(a3); \
        const float cn = fmaf(fg, c##j, ig * gv); \
        c##j = cn; \
        nh##j = og * tanhf_(cn); }

        RPTA(UNIT)
#undef UNIT
#undef MACK

#define COMMIT(i) h##i = nh##i;
        RPTA(COMMIT)
#undef COMMIT

        xt = xnext;
    }

    // FC head (4 logits)
    float l0 = b_fc[0], l1 = b_fc[1], l2 = b_fc[2], l3 = b_fc[3];
#define FCK(k) \
    l0 = fmaf(h##k, W_fc[k],       l0); \
    l1 = fmaf(h##k, W_fc[40 + k],  l1); \
    l2 = fmaf(h##k, W_fc[80 + k],  l2); \
    l3 = fmaf(h##k, W_fc[120 + k], l3);
    RPTB(FCK)
#undef FCK

    // coalesced logits store
    *reinterpret_cast<float4*>(out + (long)b * C_) = make_float4(l0, l1, l2, l3);

    // argmax (first-occurrence of max, matching jnp.argmax), as float
    int am = 0;
    float best = l0;
    if (l1 > best) { best = l1; am = 1; }
    if (l2 > best) { best = l2; am = 2; }
    if (l3 > best) { best = l3; am = 3; }
    out[(long)B_ * C_ + b] = (float)am;
}

extern "C" void kernel_launch(void* const* d_in, const int* in_sizes, int n_in,
                              void* d_out, int out_size, void* d_ws, size_t ws_size,
                              hipStream_t stream) {
    const float* x    = (const float*)d_in[0];
    const float* W_ih = (const float*)d_in[1];
    const float* W_hh = (const float*)d_in[2];
    const float* b_ih = (const float*)d_in[3];
    const float* b_hh = (const float*)d_in[4];
    const float* W_fc = (const float*)d_in[5];
    const float* b_fc = (const float*)d_in[6];
    float* out = (float*)d_out;

    dim3 block(256);
    dim3 grid(B_ / 256);
    hipLaunchKernelGGL(lstm_fused_kernel, grid, block, 0, stream,
                       x, W_ih, W_hh, b_ih, b_hh, W_fc, b_fc, out);
}

// Round 3
// 1583.654 us; speedup vs baseline: 9.7734x; 9.7734x over previous
//
#include <hip/hip_runtime.h>

// B=131072 indep LSTMs, T=40, H=40, in-dim 1, FC C=4 + argmax.
// R3: R1 spilled state (VGPR=36, scratch = 1.6GB writes). R2 fixed spill but
// fully-unrolled body (~55KB) thrashed the 32KB I$ (FETCH 3.3GB, 15-46ms).
// This version: h state in NAMED regs (k-loop unrolled, compile-time h##k);
// j-loop ROLLED (code ~1.5KB/step); runtime-indexed c[j]/h_new[j] live in a
// per-thread private LDS slice (layout [j*64+tid] -> 2-way bank alias = free),
// reloaded to named regs at step end via compile-time ds_read offsets.
// Weights: wave-uniform j -> scalar loads from K$.

#define B_ 131072
#define T_ 40
#define H_ 40
#define C_ 4
#define BLK 64

__device__ __forceinline__ float fexp2f(float v) { return __builtin_amdgcn_exp2f(v); }
__device__ __forceinline__ float frcpf(float v)  { return __builtin_amdgcn_rcpf(v); }

// sigmoid(x) = 1/(1+2^(-x*log2 e)); exact tails 0/1
__device__ __forceinline__ float sigmf(float v) {
    return frcpf(1.0f + fexp2f(-1.44269504088896340736f * v));
}
// tanh(x) = 1 - 2/(1+2^(2x*log2 e)); exact tails +/-1
__device__ __forceinline__ float tanhf_(float v) {
    return 1.0f - 2.0f * frcpf(1.0f + fexp2f(2.88539008177792681472f * v));
}

#define RPT(M) M(0) M(1) M(2) M(3) M(4) M(5) M(6) M(7) M(8) M(9) \
               M(10) M(11) M(12) M(13) M(14) M(15) M(16) M(17) M(18) M(19) \
               M(20) M(21) M(22) M(23) M(24) M(25) M(26) M(27) M(28) M(29) \
               M(30) M(31) M(32) M(33) M(34) M(35) M(36) M(37) M(38) M(39)

__global__ __launch_bounds__(BLK)
void lstm_fused_kernel(const float* __restrict__ x,
                       const float* __restrict__ W_ih,   // (160,1)
                       const float* __restrict__ W_hh,   // (160,40) row-major
                       const float* __restrict__ b_ih,   // (160,)
                       const float* __restrict__ b_hh,   // (160,)
                       const float* __restrict__ W_fc,   // (4,40) row-major
                       const float* __restrict__ b_fc,   // (4,)
                       float* __restrict__ out)          // [B*4 logits][B argmax-as-float]
{
    // per-thread private LDS slices: element j of thread tid at [j*BLK + tid]
    // bank(j,tid) = (j*64 + tid) % 32 = tid % 32 -> 2-way alias (free)
    __shared__ float cbuf[H_ * BLK];   // cell state c[j]
    __shared__ float hbuf[H_ * BLK];   // next hidden h_new[j]

    const int tid = threadIdx.x;
    const int b = blockIdx.x * BLK + tid;
    const float* xr = x + (long)b * T_;

    float* cb = cbuf + tid;   // cb[j*BLK]
    float* hb = hbuf + tid;   // hb[j*BLK]

    // named-register hidden state
#define DECLH(i) float h##i = 0.0f;
    RPT(DECLH)
#undef DECLH

    // zero-init cell state in LDS (private slice, no barrier needed)
#pragma unroll
    for (int j = 0; j < H_; ++j) cb[j * BLK] = 0.0f;

    float xt = xr[0];

#pragma unroll 1
    for (int t = 0; t < T_; ++t) {
        const int tn = (t + 1 < T_) ? (t + 1) : (T_ - 1);
        const float xnext = xr[tn];   // prefetch next scalar input

#pragma unroll 1
        for (int j = 0; j < H_; ++j) {
            // rows j, 40+j, 80+j, 120+j of W_hh; wave-uniform -> scalar loads
            const float* W0 = W_hh + j * H_;
            const float* W1 = W0 + 40 * H_;
            const float* W2 = W0 + 80 * H_;
            const float* W3 = W0 + 120 * H_;
            float a0 = fmaf(xt, W_ih[j],       b_ih[j]       + b_hh[j]);
            float a1 = fmaf(xt, W_ih[40 + j],  b_ih[40 + j]  + b_hh[40 + j]);
            float a2 = fmaf(xt, W_ih[80 + j],  b_ih[80 + j]  + b_hh[80 + j]);
            float a3 = fmaf(xt, W_ih[120 + j], b_ih[120 + j] + b_hh[120 + j]);
#define MACK(k) \
            a0 = fmaf(h##k, W0[k], a0); \
            a1 = fmaf(h##k, W1[k], a1); \
            a2 = fmaf(h##k, W2[k], a2); \
            a3 = fmaf(h##k, W3[k], a3);
            RPT(MACK)
#undef MACK
            const float ig = sigmf(a0);
            const float fg = sigmf(a1);
            const float gv = tanhf_(a2);
            const float og = sigmf(a3);
            const float cn = fmaf(fg, cb[j * BLK], ig * gv);
            cb[j * BLK] = cn;
            hb[j * BLK] = og * tanhf_(cn);
        }

        // reload h_new into named regs (compile-time ds_read offsets)
#define RELOAD(i) h##i = hb[(i) * BLK];
        RPT(RELOAD)
#undef RELOAD

        xt = xnext;
    }

    // FC head (4 logits); W_fc wave-uniform -> scalar loads
    float l0 = b_fc[0], l1 = b_fc[1], l2 = b_fc[2], l3 = b_fc[3];
#define FCK(k) \
    l0 = fmaf(h##k, W_fc[k],       l0); \
    l1 = fmaf(h##k, W_fc[40 + k],  l1); \
    l2 = fmaf(h##k, W_fc[80 + k],  l2); \
    l3 = fmaf(h##k, W_fc[120 + k], l3);
    RPT(FCK)
#undef FCK

    // coalesced logits store
    *reinterpret_cast<float4*>(out + (long)b * C_) = make_float4(l0, l1, l2, l3);

    // argmax (first occurrence of max, matching jnp.argmax), as float
    int am = 0;
    float best = l0;
    if (l1 > best) { best = l1; am = 1; }
    if (l2 > best) { best = l2; am = 2; }
    if (l3 > best) { best = l3; am = 3; }
    out[(long)B_ * C_ + b] = (float)am;
}

extern "C" void kernel_launch(void* const* d_in, const int* in_sizes, int n_in,
                              void* d_out, int out_size, void* d_ws, size_t ws_size,
                              hipStream_t stream) {
    const float* x    = (const float*)d_in[0];
    const float* W_ih = (const float*)d_in[1];
    const float* W_hh = (const float*)d_in[2];
    const float* b_ih = (const float*)d_in[3];
    const float* b_hh = (const float*)d_in[4];
    const float* W_fc = (const float*)d_in[5];
    const float* b_fc = (const float*)d_in[6];
    float* out = (float*)d_out;

    dim3 block(BLK);
    dim3 grid(B_ / BLK);
    hipLaunchKernelGGL(lstm_fused_kernel, grid, block, 0, stream,
                       x, W_ih, W_hh, b_ih, b_hh, W_fc, b_fc, out);
}